// Round 19
// baseline (67.081 us; speedup 1.0000x reference)
//
#include <hip/hip_runtime.h>

namespace {
constexpr int N_ = 8, C_ = 32, H_ = 256, W_ = 512, DISP_ = 25;
constexpr int CH = H_ * W_;   // elements between channels / disparities
constexpr int NSS = C_ / 2;   // 16 supersteps, 2 channels packed per step
constexpr int YOFF = 512;     // y region start (u32 units) inside a buffer
constexpr int YST = 536;      // staged y cols: [-12, 524)
constexpr int BUF = 1056;     // u32 stride per buffer (512 x + 536 y + pad)
}

typedef __attribute__((ext_vector_type(2))) _Float16 h2;
typedef __attribute__((ext_vector_type(4))) float f4;  // native vector for nt-store

__device__ __forceinline__ h2 u2h(unsigned u) { return __builtin_bit_cast(h2, u); }
__device__ __forceinline__ unsigned h2u(h2 v) { return __builtin_bit_cast(unsigned, v); }

// r19 = r18 (packed-f16 pairs + fdot2 + nt-stores, 66.2 us) with full-row
// blocks: 512 threads stage one whole (n,h) row per superstep (512 x cols +
// 536 y halo cols as f16x2), halving block count (2048), barrier count, and
// halo overhead. r18 post-mortem: all pipes at 50-60% in the real run ->
// phase serialization (~1.7x over the 38us HBM floor) is the remaining cost;
// this shaves phases/halo at constant register footprint (cap 64 under
// (512,8); r18 measured 32 arch VGPR, no spill — WRITE_SIZE is the tripwire).
//   tl = tid & 127 -> 4 output cols (w0 = 4*tl); g = tid>>7 -> disparity grp
//   G0: i in [0,7) OFF +4 | G1: [7,13) OFF 0 | G2: [13,19) OFF -8
//   G3: [19,25) OFF -12;  y window u32 idx m = cw + 12 - i - OFF in [0,12)
// y slot s holds col s-12 (clamped at edges; clamped cols only feed
// epilogue-zeroed outputs). Window base slot jb = w0 + OFF + 12 (16B-aligned).
template <int G>
__device__ __forceinline__ void body(const float* px, const float* py0,
                                     const float* py1, bool extra,
                                     float* __restrict__ op, unsigned* lds,
                                     int tid, int w0) {
  constexpr int I0 = (G == 0) ? 0 : (G == 1) ? 7 : (G == 2) ? 13 : 19;
  constexpr int NI = (G == 0) ? 7 : 6;
  constexpr int OFF = (G == 0) ? 4 : (G == 1) ? 0 : (G == 2) ? -8 : -12;

  const h2 one = {(_Float16)1.0f, (_Float16)1.0f};

  float acc[NI][4];
#pragma unroll
  for (int il = 0; il < NI; ++il)
#pragma unroll
    for (int cw = 0; cw < 4; ++cw) acc[il][cw] = 0.0f;

  float a0, a1, b0, b1, c0, c1;

#define SLOAD()                                                           \
  do {                                                                    \
    a0 = px[0]; a1 = px[CH];                                              \
    b0 = py0[0]; b1 = py0[CH];                                            \
    if (extra) { c0 = py1[0]; c1 = py1[CH]; }                             \
    px += 2 * CH; py0 += 2 * CH; py1 += 2 * CH;                           \
  } while (0)

#define SWRITE(bsel)                                                      \
  do {                                                                    \
    unsigned* wp = lds + (bsel)*BUF;                                      \
    wp[tid] = __builtin_bit_cast(unsigned,                                \
                                 __builtin_amdgcn_cvt_pkrtz(a0, a1));     \
    wp[YOFF + tid] = __builtin_bit_cast(unsigned,                         \
                                        __builtin_amdgcn_cvt_pkrtz(b0, b1)); \
    if (extra)                                                            \
      wp[YOFF + 512 + tid] = __builtin_bit_cast(                          \
          unsigned, __builtin_amdgcn_cvt_pkrtz(c0, c1));                  \
  } while (0)

#define COMPUTE(bsel)                                                     \
  do {                                                                    \
    const unsigned* bp = lds + (bsel)*BUF;                                \
    const uint4 xq = *reinterpret_cast<const uint4*>(bp + w0);            \
    const unsigned* yp = bp + YOFF + w0 + (OFF + 12);                     \
    const uint4 q0 = *reinterpret_cast<const uint4*>(yp);                 \
    const uint4 q1 = *reinterpret_cast<const uint4*>(yp + 4);             \
    const uint4 q2 = *reinterpret_cast<const uint4*>(yp + 8);             \
    const unsigned xs[4] = {xq.x, xq.y, xq.z, xq.w};                      \
    const unsigned yw[12] = {q0.x, q0.y, q0.z, q0.w, q1.x, q1.y, q1.z,    \
                             q1.w, q2.x, q2.y, q2.z, q2.w};               \
    _Pragma("unroll") for (int il = 0; il < NI; ++il) {                   \
      _Pragma("unroll") for (int cw = 0; cw < 4; ++cw) {                  \
        h2 d = u2h(xs[cw]) - u2h(yw[cw + 12 - (I0 + il) - OFF]);          \
        h2 a = u2h(h2u(d) & 0x7FFF7FFFu);                                 \
        acc[il][cw] = __builtin_amdgcn_fdot2(a, one, acc[il][cw], false); \
      }                                                                   \
    }                                                                     \
  } while (0)

  // Prologue: stage superstep 0 into buffer 0.
  SLOAD();
  SWRITE(0);
  __syncthreads();

  int cb = 0;
#pragma unroll 1
  for (int s = 0; s < NSS; ++s) {
    const bool more = (s + 1 < NSS);
    if (more) SLOAD();   // issue next superstep's global loads early
    COMPUTE(cb);         // compute hides the load latency
    if (more) SWRITE(cb ^ 1);
    __syncthreads();     // writes visible; buffer reuse ordered
    cb ^= 1;
  }

#undef SLOAD
#undef SWRITE
#undef COMPUTE

  // Epilogue: zero out-of-overlap (w,i) pairs; NON-TEMPORAL stores (output
  // is write-once/never-read -> evict-first keeps it out of L2/L3).
#pragma unroll
  for (int il = 0; il < NI; ++il) {
    const int i = I0 + il;
    const int j0 = w0 - i + 12;  // y column used by cw=0
    f4 v;
    v.x = ((unsigned)(j0 + 0) < (unsigned)W_) ? acc[il][0] : 0.0f;
    v.y = ((unsigned)(j0 + 1) < (unsigned)W_) ? acc[il][1] : 0.0f;
    v.z = ((unsigned)(j0 + 2) < (unsigned)W_) ? acc[il][2] : 0.0f;
    v.w = ((unsigned)(j0 + 3) < (unsigned)W_) ? acc[il][3] : 0.0f;
    __builtin_nontemporal_store(v, reinterpret_cast<f4*>(op + (size_t)i * CH));
  }
}

__global__ __launch_bounds__(512, 8) void rescost_kernel(
    const float* __restrict__ x, const float* __restrict__ y,
    float* __restrict__ out) {
  __shared__ __align__(16) unsigned lds[2 * BUF];  // 8448 B

  const int tid = threadIdx.x;
  const int tl = tid & 127;  // column group: w0 = 4*tl
  const int g = tid >> 7;    // disparity group (wave-uniform: 2 waves/group)
  const int r = blockIdx.x;  // row in [0, N*H)
  const int n = r >> 8;      // H = 256
  const int h = r & (H_ - 1);
  const int w0 = tl << 2;

  const size_t row_base = ((size_t)n * C_ * H_ + (size_t)h) * W_;

  // Staging columns. x: col tid. y: slot tid -> col tid-12; extra slots
  // 512+tid (tid<24) -> col 500+tid. Edge clamps only feed zeroed outputs.
  int gy0 = tid - 12;
  gy0 = gy0 < 0 ? 0 : (gy0 > W_ - 1 ? W_ - 1 : gy0);
  int gy1 = 500 + tid;
  gy1 = gy1 > W_ - 1 ? W_ - 1 : gy1;
  const bool extra = tid < (YST - 512);  // 24 threads stage the y tail

  const float* px = x + row_base + tid;
  const float* py0 = y + row_base + gy0;
  const float* py1 = y + row_base + gy1;
  float* op = out + (size_t)n * DISP_ * CH + (size_t)h * W_ + w0;

  if (g == 0)
    body<0>(px, py0, py1, extra, op, lds, tid, w0);
  else if (g == 1)
    body<1>(px, py0, py1, extra, op, lds, tid, w0);
  else if (g == 2)
    body<2>(px, py0, py1, extra, op, lds, tid, w0);
  else
    body<3>(px, py0, py1, extra, op, lds, tid, w0);
}

extern "C" void kernel_launch(void* const* d_in, const int* in_sizes, int n_in,
                              void* d_out, int out_size, void* d_ws, size_t ws_size,
                              hipStream_t stream) {
  const float* x = (const float*)d_in[0];
  const float* y = (const float*)d_in[1];
  float* out = (float*)d_out;
  dim3 grid(N_ * H_);  // one full (n,h) row per 512-thread block
  dim3 block(512);
  hipLaunchKernelGGL(rescost_kernel, grid, block, 0, stream, x, y, out);
}